// Round 8
// baseline (137.282 us; speedup 1.0000x reference)
//
#include <hip/hip_runtime.h>
#include <math.h>

#define NP 8      // paths
#define ND 128    // D = c / P
#define NC 1024   // channels = NP*ND
#define NL 4096   // sequence length
#define NB 16     // batch
#define LN_EPS 1e-5f

#define NBLK 2048           // 8 blocks/CU x 256 CUs (full co-residency)
#define NCHUNK 8            // chunks of 2 batches; 1 row per block per chunk
#define GRPS 64             // barrier groups (32 blocks each)

typedef float v4f __attribute__((ext_vector_type(4)));

__device__ __forceinline__ float hsum(v4f v) { return v.x + v.y + v.z + v.w; }
__device__ __forceinline__ float sigmoid_f(float z) { return 1.f / (1.f + expf(-z)); }

// expf-only tanh-GELU (no erff libcall). |err| ~1e-3 << 2.8e-2 threshold.
__device__ __forceinline__ float gelu_f(float s) {
    const float t = 0.7978845608028654f * (s + 0.044715f * s * s * s);
    const float e = expf(2.f * t);
    return 0.5f * s * (1.f + (e - 1.f) / (e + 1.f));
}

// ================= Persistent fused cooperative kernel =================
// Per chunk c (2 batches): block i owns row rowc = c*2048 + i.
//  1) pool rowc from HBM into 4 v4f REGISTERS (16 VGPRs) -> y[rowc]
//  2) 2-level grid barrier (monotonic counters)
//  3) per-block redundant: attn over own batch's 1024 channels (from y),
//     per-path means, LN+MLP+gate distributed across lanes via LDS
//  4) scale the register-resident row, nontemporal store
__global__ __launch_bounds__(256, 8) void fused_kernel(
    const float* __restrict__ x, float* __restrict__ y,
    unsigned* __restrict__ garr, unsigned* __restrict__ root,
    const float* __restrict__ conv1_w, const float* __restrict__ conv2_w,
    const float* __restrict__ combine_w, const float* __restrict__ combine_b,
    const float* __restrict__ ln_g, const float* __restrict__ ln_b,
    const float* __restrict__ W1, const float* __restrict__ b1,
    const float* __restrict__ W2, const float* __restrict__ b2,
    float* __restrict__ out)
{
    const int tid = threadIdx.x;
    const int bid = blockIdx.x;
    const int grp = bid >> 5;            // 32 blocks per barrier group

    __shared__ float sred[4];
    __shared__ float sy[NC];
    __shared__ float sattn[NC];
    __shared__ float scross[NP];
    __shared__ float sh[NP];
    __shared__ float sh2[2 * NP];
    __shared__ float sgate[NP];
    __shared__ float sml[2];             // mu, inv

    for (int c = 0; c < NCHUNK; ++c) {
        const int rowc = c * NBLK + bid;          // global row
        const int b    = rowc >> 10;              // batch
        const int ch0  = rowc & (NC - 1);         // channel within batch
        const v4f* xb  = (const v4f*)x + (size_t)rowc * (NL / 4);
        v4f* ob        = (v4f*)out    + (size_t)rowc * (NL / 4);

        // ---- 1) pool one row; payload stays in registers ----
        v4f a0 = xb[tid], a1 = xb[tid + 256], a2 = xb[tid + 512], a3 = xb[tid + 768];
        {
            float ps = hsum(a0) + hsum(a1) + hsum(a2) + hsum(a3);
            ps += __shfl_down(ps, 32, 64); ps += __shfl_down(ps, 16, 64);
            ps += __shfl_down(ps, 8, 64);  ps += __shfl_down(ps, 4, 64);
            ps += __shfl_down(ps, 2, 64);  ps += __shfl_down(ps, 1, 64);
            if ((tid & 63) == 0) sred[tid >> 6] = ps;
        }
        __syncthreads();
        if (tid == 0) {
            y[rowc] = (sred[0] + sred[1] + sred[2] + sred[3]) * (1.f / NL);
            __threadfence();             // release y to device scope
            // ---- 2) two-level grid barrier (monotonic) ----
            unsigned old = __hip_atomic_fetch_add(&garr[grp], 1u,
                              __ATOMIC_RELEASE, __HIP_MEMORY_SCOPE_AGENT);
            if (old == (unsigned)(c * 32 + 31))   // last block of group, this chunk
                __hip_atomic_fetch_add(root, 1u,
                              __ATOMIC_RELEASE, __HIP_MEMORY_SCOPE_AGENT);
            while (__hip_atomic_load(root, __ATOMIC_ACQUIRE,
                                     __HIP_MEMORY_SCOPE_AGENT) < (unsigned)((c + 1) * GRPS))
                __builtin_amdgcn_s_sleep(2);
        }
        __syncthreads();

        // ---- 3) attn + gate for this block's batch (redundant per block) ----
        const float* yb = y + b * NC;
        #pragma unroll
        for (int k = 0; k < 4; ++k) {
            const int i = tid + 256 * k;   // agent-scope: dodge stale XCD-L2 lines
            sy[i] = __hip_atomic_load(&yb[i], __ATOMIC_RELAXED, __HIP_MEMORY_SCOPE_AGENT);
        }
        __syncthreads();
        #pragma unroll
        for (int k = 0; k < 4; ++k) {
            const int pos = tid + 256 * k;
            const int p = pos >> 7, d = pos & 127;
            const float* rowp = sy + p * ND;
            float c1 = 0.f;
            #pragma unroll
            for (int t = 0; t < 5; ++t) {
                int dd = d + t - 2;
                float v = (dd >= 0 && dd < ND) ? rowp[dd] : 0.f;
                c1 += conv1_w[p * 5 + t] * v;
            }
            float c2 = 0.f;
            #pragma unroll
            for (int t = 0; t < 9; ++t) {
                int dd = d + t - 4;
                float v = (dd >= 0 && dd < ND) ? rowp[dd] : 0.f;
                c2 += conv2_w[p * 9 + t] * v;
            }
            sattn[pos] = sigmoid_f(combine_w[0] * c1 + combine_w[1] * c2 + combine_b[0]);
        }
        __syncthreads();
        if (tid < 128) {                 // per-path means: 16 lanes/path, 8 elems each
            const int p = tid >> 4, o = (tid & 15) * 8;
            float s = 0.f;
            #pragma unroll
            for (int j = 0; j < 8; ++j) s += sattn[p * ND + o + j];
            s += __shfl_down(s, 8, 16); s += __shfl_down(s, 4, 16);
            s += __shfl_down(s, 2, 16); s += __shfl_down(s, 1, 16);
            if ((tid & 15) == 0) scross[p] = s * (1.f / ND);
        }
        __syncthreads();
        if (tid == 0) {                  // LN stats (no private arrays)
            float mu = 0.f;
            #pragma unroll
            for (int pp = 0; pp < NP; ++pp) mu += scross[pp];
            mu *= (1.f / NP);
            float var = 0.f;
            #pragma unroll
            for (int pp = 0; pp < NP; ++pp) { float dl = scross[pp] - mu; var += dl * dl; }
            sml[0] = mu;
            sml[1] = rsqrtf(var * (1.f / NP) + LN_EPS);
        }
        __syncthreads();
        if (tid < NP)
            sh[tid] = (scross[tid] - sml[0]) * sml[1] * ln_g[tid] + ln_b[tid];
        __syncthreads();
        if (tid < 2 * NP) {
            float s = b1[tid];
            #pragma unroll
            for (int pp = 0; pp < NP; ++pp) s += sh[pp] * W1[pp * (2 * NP) + tid];
            sh2[tid] = gelu_f(s);
        }
        __syncthreads();
        if (tid < NP) {
            float s = b2[tid];
            #pragma unroll
            for (int j = 0; j < 2 * NP; ++j) s += sh2[j] * W2[j * NP + tid];
            sgate[tid] = sigmoid_f(s);
        }
        __syncthreads();

        // ---- 4) scale register-resident row, stream out ----
        const float s = sattn[ch0] * sgate[ch0 >> 7];
        __builtin_nontemporal_store(a0 * s, &ob[tid]);
        __builtin_nontemporal_store(a1 * s, &ob[tid + 256]);
        __builtin_nontemporal_store(a2 * s, &ob[tid + 512]);
        __builtin_nontemporal_store(a3 * s, &ob[tid + 768]);
        __syncthreads();                 // protect LDS before next chunk reuses it
    }
}

// ================= Fallback path (R4 kernels, 133 us) =================
__global__ __launch_bounds__(256) void pool_kernel(const float* __restrict__ x,
                                                   float* __restrict__ y) {
    const int wid  = threadIdx.x >> 6;
    const int lane = threadIdx.x & 63;
    const int row  = blockIdx.x * 4 + wid;
    const v4f* xr = (const v4f*)(x + (size_t)row * NL);
    float s = 0.f;
    #pragma unroll
    for (int i = 0; i < 16; ++i) {
        v4f v = xr[lane + i * 64];
        s += v.x + v.y + v.z + v.w;
    }
    #pragma unroll
    for (int off = 32; off; off >>= 1) s += __shfl_down(s, off, 64);
    if (lane == 0) y[row] = s * (1.f / NL);
}

__global__ __launch_bounds__(1024) void attn_kernel(
    const float* __restrict__ y,
    const float* __restrict__ conv1_w, const float* __restrict__ conv2_w,
    const float* __restrict__ combine_w, const float* __restrict__ combine_b,
    const float* __restrict__ ln_g, const float* __restrict__ ln_b,
    const float* __restrict__ W1, const float* __restrict__ b1,
    const float* __restrict__ W2, const float* __restrict__ b2,
    float* __restrict__ scale)
{
    const int b = blockIdx.x;
    const int tid = threadIdx.x;
    const int p = tid >> 7;
    const int d = tid & 127;

    __shared__ float sy[NC];
    __shared__ float sattn[NC];
    __shared__ float sred[16];
    __shared__ float scross[NP];
    __shared__ float sh[NP];
    __shared__ float sh2[2 * NP];
    __shared__ float sgate[NP];
    __shared__ float sml[2];

    sy[tid] = y[b * NC + tid];
    __syncthreads();

    const float* rowp = sy + p * ND;
    float c1 = 0.f;
    #pragma unroll
    for (int t = 0; t < 5; ++t) {
        int dd = d + t - 2;
        float v = (dd >= 0 && dd < ND) ? rowp[dd] : 0.f;
        c1 += conv1_w[p * 5 + t] * v;
    }
    float c2 = 0.f;
    #pragma unroll
    for (int t = 0; t < 9; ++t) {
        int dd = d + t - 4;
        float v = (dd >= 0 && dd < ND) ? rowp[dd] : 0.f;
        c2 += conv2_w[p * 9 + t] * v;
    }
    const float a = sigmoid_f(combine_w[0] * c1 + combine_w[1] * c2 + combine_b[0]);
    sattn[tid] = a;

    float r = a;
    #pragma unroll
    for (int off = 32; off; off >>= 1) r += __shfl_down(r, off, 64);
    const int lane = tid & 63, wid = tid >> 6;
    if (lane == 0) sred[wid] = r;
    __syncthreads();

    if (tid == 0) {
        float mu = 0.f, var = 0.f;
        #pragma unroll
        for (int pp = 0; pp < NP; ++pp) {
            scross[pp] = (sred[2 * pp] + sred[2 * pp + 1]) * (1.f / ND);
            mu += scross[pp];
        }
        mu *= (1.f / NP);
        #pragma unroll
        for (int pp = 0; pp < NP; ++pp) { float dl = scross[pp] - mu; var += dl * dl; }
        sml[0] = mu;
        sml[1] = rsqrtf(var * (1.f / NP) + LN_EPS);
    }
    __syncthreads();
    if (tid < NP)
        sh[tid] = (scross[tid] - sml[0]) * sml[1] * ln_g[tid] + ln_b[tid];
    __syncthreads();
    if (tid < 2 * NP) {
        float s = b1[tid];
        #pragma unroll
        for (int pp = 0; pp < NP; ++pp) s += sh[pp] * W1[pp * (2 * NP) + tid];
        sh2[tid] = gelu_f(s);
    }
    __syncthreads();
    if (tid < NP) {
        float s = b2[tid];
        #pragma unroll
        for (int j = 0; j < 2 * NP; ++j) s += sh2[j] * W2[j * NP + tid];
        sgate[tid] = sigmoid_f(s);
    }
    __syncthreads();

    scale[b * NC + tid] = sattn[tid] * sgate[p];
}

__global__ __launch_bounds__(256) void scale_kernel(const float* __restrict__ x,
                                                    const float* __restrict__ scale,
                                                    float* __restrict__ out) {
    const v4f* xv = (const v4f*)x;
    v4f* ov = (v4f*)out;
    const size_t n = (size_t)NB * NC * (NL / 4);
    const size_t stride = (size_t)gridDim.x * blockDim.x;
    for (size_t i = (size_t)blockIdx.x * blockDim.x + threadIdx.x; i < n; i += stride) {
        const float s = scale[i >> 10];
        v4f v = xv[i];
        v *= s;
        __builtin_nontemporal_store(v, &ov[i]);
    }
}

extern "C" void kernel_launch(void* const* d_in, const int* in_sizes, int n_in,
                              void* d_out, int out_size, void* d_ws, size_t ws_size,
                              hipStream_t stream) {
    const float* x         = (const float*)d_in[0];
    const float* conv1_w   = (const float*)d_in[1];
    const float* conv2_w   = (const float*)d_in[2];
    const float* combine_w = (const float*)d_in[3];
    const float* combine_b = (const float*)d_in[4];
    const float* ln_g      = (const float*)d_in[5];
    const float* ln_b      = (const float*)d_in[6];
    const float* W1        = (const float*)d_in[7];
    const float* b1        = (const float*)d_in[8];
    const float* W2        = (const float*)d_in[9];
    const float* b2        = (const float*)d_in[10];
    float* out = (float*)d_out;

    float* y        = (float*)d_ws;                    // [0,64KB): pooled means
    float* scale    = y + NB * NC;                     // [64KB,128KB): fallback only
    unsigned* garr  = (unsigned*)(void*)(((char*)d_ws) + (NB * NC) * sizeof(float));
    unsigned* root  = garr + GRPS;                     // barrier counters (coop path)

    // zero barrier counters each launch (graph-capturable, deterministic)
    hipMemsetAsync((void*)garr, 0, (GRPS + 16) * sizeof(unsigned), stream);

    int nb = 0;
    hipOccupancyMaxActiveBlocksPerMultiprocessor(&nb, fused_kernel, 256, 0);
    if (nb >= NBLK / 256) {
        void* args[] = { (void*)&x, (void*)&y, (void*)&garr, (void*)&root,
                         (void*)&conv1_w, (void*)&conv2_w,
                         (void*)&combine_w, (void*)&combine_b,
                         (void*)&ln_g, (void*)&ln_b,
                         (void*)&W1, (void*)&b1, (void*)&W2, (void*)&b2,
                         (void*)&out };
        hipLaunchCooperativeKernel((const void*)fused_kernel, dim3(NBLK), dim3(256),
                                   args, 0, stream);
    } else {
        pool_kernel<<<NB * NC / 4, 256, 0, stream>>>(x, y);
        attn_kernel<<<NB, 1024, 0, stream>>>(y, conv1_w, conv2_w, combine_w, combine_b,
                                             ln_g, ln_b, W1, b1, W2, b2, scale);
        scale_kernel<<<2048, 256, 0, stream>>>(x, scale, out);
    }
}

// Round 9
// 135.273 us; speedup vs baseline: 1.0149x; 1.0149x over previous
//
#include <hip/hip_runtime.h>
#include <math.h>

#define NP 8      // paths
#define ND 128    // D = c / P
#define NC 1024   // channels = NP*ND
#define NL 4096   // sequence length
#define NB 16     // batch
#define LN_EPS 1e-5f

#define NBLK 2048           // 8 blocks/CU x 256 CUs (full co-residency)
#define NCHUNK 8            // 1 row per block per chunk
#define GRPS 64             // barrier groups (32 blocks each)

typedef float v4f __attribute__((ext_vector_type(4)));

__device__ __forceinline__ float hsum(v4f v) { return v.x + v.y + v.z + v.w; }
__device__ __forceinline__ float sigmoid_f(float z) { return 1.f / (1.f + expf(-z)); }

// expf-only tanh-GELU (no erff libcall). |err| ~1e-3 << 2.8e-2 threshold.
__device__ __forceinline__ float gelu_f(float s) {
    const float t = 0.7978845608028654f * (s + 0.044715f * s * s * s);
    const float e = expf(2.f * t);
    return 0.5f * s * (1.f + (e - 1.f) / (e + 1.f));
}

// ================= Persistent fused cooperative kernel (pipelined) ==========
// Per chunk c: block owns row rowc = c*2048 + bid.
//   pool rowc (regs a0..a3) -> y[rowc]; arrive barrier;
//   ISSUE next chunk's loads (n0..n3);           <-- in flight during wait
//   wait barrier; attn+gate from y (redundant per block);
//   scale a0..a3, nt-store; rotate a<-n.
__global__ __launch_bounds__(256, 8) void fused_kernel(
    const float* __restrict__ x, float* __restrict__ y,
    unsigned* __restrict__ garr, unsigned* __restrict__ grel,
    unsigned* __restrict__ root,
    const float* __restrict__ conv1_w, const float* __restrict__ conv2_w,
    const float* __restrict__ combine_w, const float* __restrict__ combine_b,
    const float* __restrict__ ln_g, const float* __restrict__ ln_b,
    const float* __restrict__ W1, const float* __restrict__ b1,
    const float* __restrict__ W2, const float* __restrict__ b2,
    float* __restrict__ out)
{
    const int tid    = threadIdx.x;
    const int bid    = blockIdx.x;
    const int grp    = bid >> 5;             // 32 blocks per group
    const bool lead  = (bid & 31) == 0;

    __shared__ float sred[4];
    __shared__ float sy[NC];
    __shared__ float sattn[NC];
    __shared__ float scross[NP];
    __shared__ float sh[NP];
    __shared__ float sh2[2 * NP];
    __shared__ float sgate[NP];
    __shared__ float sml[2];                 // mu, inv

    const size_t rstride = (size_t)NBLK * (NL / 4);   // v4f stride between chunks

    const v4f* xb = (const v4f*)x + (size_t)bid * (NL / 4);
    v4f* ob       = (v4f*)out    + (size_t)bid * (NL / 4);

    // prologue: load chunk 0 row
    v4f a0 = xb[tid], a1 = xb[tid + 256], a2 = xb[tid + 512], a3 = xb[tid + 768];
    v4f n0, n1, n2, n3;

    for (int c = 0; c < NCHUNK; ++c) {
        const int rowc = c * NBLK + bid;
        const int b    = rowc >> 10;
        const int ch0  = rowc & (NC - 1);

        // ---- pool current row (regs) ----
        {
            float ps = hsum(a0) + hsum(a1) + hsum(a2) + hsum(a3);
            ps += __shfl_down(ps, 32, 64); ps += __shfl_down(ps, 16, 64);
            ps += __shfl_down(ps, 8, 64);  ps += __shfl_down(ps, 4, 64);
            ps += __shfl_down(ps, 2, 64);  ps += __shfl_down(ps, 1, 64);
            if ((tid & 63) == 0) sred[tid >> 6] = ps;
        }
        __syncthreads();
        if (tid == 0) {
            const float ym = (sred[0] + sred[1] + sred[2] + sred[3]) * (1.f / NL);
            __hip_atomic_store(&y[rowc], ym, __ATOMIC_RELAXED, __HIP_MEMORY_SCOPE_AGENT);
            // arrive (release orders the y store before the count is seen)
            unsigned old = __hip_atomic_fetch_add(&garr[grp], 1u,
                              __ATOMIC_RELEASE, __HIP_MEMORY_SCOPE_AGENT);
            if (old == (unsigned)(c * 32 + 31))
                __hip_atomic_fetch_add(root, 1u,
                              __ATOMIC_RELEASE, __HIP_MEMORY_SCOPE_AGENT);
        }

        // ---- issue next chunk's loads BEFORE waiting (hide under barrier) ----
        if (c + 1 < NCHUNK) {
            const v4f* xn = xb + (size_t)(c + 1) * rstride;
            n0 = xn[tid]; n1 = xn[tid + 256]; n2 = xn[tid + 512]; n3 = xn[tid + 768];
        }

        // ---- two-level wait (leaders on root, followers on per-group line) ----
        if (tid == 0) {
            if (lead) {
                while (__hip_atomic_load(root, __ATOMIC_RELAXED,
                                         __HIP_MEMORY_SCOPE_AGENT) < (unsigned)((c + 1) * GRPS))
                    __builtin_amdgcn_s_sleep(4);
                __hip_atomic_store(&grel[grp], (unsigned)(c + 1),
                                   __ATOMIC_RELAXED, __HIP_MEMORY_SCOPE_AGENT);
            } else {
                while (__hip_atomic_load(&grel[grp], __ATOMIC_RELAXED,
                                         __HIP_MEMORY_SCOPE_AGENT) < (unsigned)(c + 1))
                    __builtin_amdgcn_s_sleep(4);
            }
        }
        __syncthreads();

        // ---- attn + gate for this block's batch (redundant per block) ----
        const float* yb = y + b * NC;
        #pragma unroll
        for (int k = 0; k < 4; ++k) {
            const int i = tid + 256 * k;    // agent-scope: dodge stale XCD-L2 lines
            sy[i] = __hip_atomic_load(&yb[i], __ATOMIC_RELAXED, __HIP_MEMORY_SCOPE_AGENT);
        }
        __syncthreads();
        #pragma unroll
        for (int k = 0; k < 4; ++k) {
            const int pos = tid + 256 * k;
            const int p = pos >> 7, d = pos & 127;
            const float* rowp = sy + p * ND;
            float c1 = 0.f;
            #pragma unroll
            for (int t = 0; t < 5; ++t) {
                int dd = d + t - 2;
                float v = (dd >= 0 && dd < ND) ? rowp[dd] : 0.f;
                c1 += conv1_w[p * 5 + t] * v;
            }
            float c2 = 0.f;
            #pragma unroll
            for (int t = 0; t < 9; ++t) {
                int dd = d + t - 4;
                float v = (dd >= 0 && dd < ND) ? rowp[dd] : 0.f;
                c2 += conv2_w[p * 9 + t] * v;
            }
            sattn[pos] = sigmoid_f(combine_w[0] * c1 + combine_w[1] * c2 + combine_b[0]);
        }
        __syncthreads();
        if (tid < 128) {                    // per-path means: 16 lanes/path, 8 elems each
            const int p = tid >> 4, o = (tid & 15) * 8;
            float s = 0.f;
            #pragma unroll
            for (int j = 0; j < 8; ++j) s += sattn[p * ND + o + j];
            s += __shfl_down(s, 8, 16); s += __shfl_down(s, 4, 16);
            s += __shfl_down(s, 2, 16); s += __shfl_down(s, 1, 16);
            if ((tid & 15) == 0) scross[p] = s * (1.f / ND);
        }
        __syncthreads();
        if (tid == 0) {
            float mu = 0.f;
            #pragma unroll
            for (int pp = 0; pp < NP; ++pp) mu += scross[pp];
            mu *= (1.f / NP);
            float var = 0.f;
            #pragma unroll
            for (int pp = 0; pp < NP; ++pp) { float dl = scross[pp] - mu; var += dl * dl; }
            sml[0] = mu;
            sml[1] = rsqrtf(var * (1.f / NP) + LN_EPS);
        }
        __syncthreads();
        if (tid < NP)
            sh[tid] = (scross[tid] - sml[0]) * sml[1] * ln_g[tid] + ln_b[tid];
        __syncthreads();
        if (tid < 2 * NP) {
            float s = b1[tid];
            #pragma unroll
            for (int pp = 0; pp < NP; ++pp) s += sh[pp] * W1[pp * (2 * NP) + tid];
            sh2[tid] = gelu_f(s);
        }
        __syncthreads();
        if (tid < NP) {
            float s = b2[tid];
            #pragma unroll
            for (int j = 0; j < 2 * NP; ++j) s += sh2[j] * W2[j * NP + tid];
            sgate[tid] = sigmoid_f(s);
        }
        __syncthreads();

        // ---- scale register-resident row, stream out ----
        {
            const float s = sattn[ch0] * sgate[ch0 >> 7];
            v4f* oc = ob + (size_t)c * rstride;
            __builtin_nontemporal_store(a0 * s, &oc[tid]);
            __builtin_nontemporal_store(a1 * s, &oc[tid + 256]);
            __builtin_nontemporal_store(a2 * s, &oc[tid + 512]);
            __builtin_nontemporal_store(a3 * s, &oc[tid + 768]);
        }
        // rotate pipeline registers
        a0 = n0; a1 = n1; a2 = n2; a3 = n3;
        __syncthreads();                    // protect LDS before next chunk reuses it
    }
}

// ================= Fallback path (R4 kernels, 133 us) =================
__global__ __launch_bounds__(256) void pool_kernel(const float* __restrict__ x,
                                                   float* __restrict__ y) {
    const int wid  = threadIdx.x >> 6;
    const int lane = threadIdx.x & 63;
    const int row  = blockIdx.x * 4 + wid;
    const v4f* xr = (const v4f*)(x + (size_t)row * NL);
    float s = 0.f;
    #pragma unroll
    for (int i = 0; i < 16; ++i) {
        v4f v = xr[lane + i * 64];
        s += v.x + v.y + v.z + v.w;
    }
    #pragma unroll
    for (int off = 32; off; off >>= 1) s += __shfl_down(s, off, 64);
    if (lane == 0) y[row] = s * (1.f / NL);
}

__global__ __launch_bounds__(1024) void attn_kernel(
    const float* __restrict__ y,
    const float* __restrict__ conv1_w, const float* __restrict__ conv2_w,
    const float* __restrict__ combine_w, const float* __restrict__ combine_b,
    const float* __restrict__ ln_g, const float* __restrict__ ln_b,
    const float* __restrict__ W1, const float* __restrict__ b1,
    const float* __restrict__ W2, const float* __restrict__ b2,
    float* __restrict__ scale)
{
    const int b = blockIdx.x;
    const int tid = threadIdx.x;
    const int p = tid >> 7;
    const int d = tid & 127;

    __shared__ float sy[NC];
    __shared__ float sattn[NC];
    __shared__ float sred[16];
    __shared__ float scross[NP];
    __shared__ float sh[NP];
    __shared__ float sh2[2 * NP];
    __shared__ float sgate[NP];
    __shared__ float sml[2];

    sy[tid] = y[b * NC + tid];
    __syncthreads();

    const float* rowp = sy + p * ND;
    float c1 = 0.f;
    #pragma unroll
    for (int t = 0; t < 5; ++t) {
        int dd = d + t - 2;
        float v = (dd >= 0 && dd < ND) ? rowp[dd] : 0.f;
        c1 += conv1_w[p * 5 + t] * v;
    }
    float c2 = 0.f;
    #pragma unroll
    for (int t = 0; t < 9; ++t) {
        int dd = d + t - 4;
        float v = (dd >= 0 && dd < ND) ? rowp[dd] : 0.f;
        c2 += conv2_w[p * 9 + t] * v;
    }
    const float a = sigmoid_f(combine_w[0] * c1 + combine_w[1] * c2 + combine_b[0]);
    sattn[tid] = a;

    float r = a;
    #pragma unroll
    for (int off = 32; off; off >>= 1) r += __shfl_down(r, off, 64);
    const int lane = tid & 63, wid = tid >> 6;
    if (lane == 0) sred[wid] = r;
    __syncthreads();

    if (tid == 0) {
        float mu = 0.f, var = 0.f;
        #pragma unroll
        for (int pp = 0; pp < NP; ++pp) {
            scross[pp] = (sred[2 * pp] + sred[2 * pp + 1]) * (1.f / ND);
            mu += scross[pp];
        }
        mu *= (1.f / NP);
        #pragma unroll
        for (int pp = 0; pp < NP; ++pp) { float dl = scross[pp] - mu; var += dl * dl; }
        sml[0] = mu;
        sml[1] = rsqrtf(var * (1.f / NP) + LN_EPS);
    }
    __syncthreads();
    if (tid < NP)
        sh[tid] = (scross[tid] - sml[0]) * sml[1] * ln_g[tid] + ln_b[tid];
    __syncthreads();
    if (tid < 2 * NP) {
        float s = b1[tid];
        #pragma unroll
        for (int pp = 0; pp < NP; ++pp) s += sh[pp] * W1[pp * (2 * NP) + tid];
        sh2[tid] = gelu_f(s);
    }
    __syncthreads();
    if (tid < NP) {
        float s = b2[tid];
        #pragma unroll
        for (int j = 0; j < 2 * NP; ++j) s += sh2[j] * W2[j * NP + tid];
        sgate[tid] = sigmoid_f(s);
    }
    __syncthreads();

    scale[b * NC + tid] = sattn[tid] * sgate[p];
}

__global__ __launch_bounds__(256) void scale_kernel(const float* __restrict__ x,
                                                    const float* __restrict__ scale,
                                                    float* __restrict__ out) {
    const v4f* xv = (const v4f*)x;
    v4f* ov = (v4f*)out;
    const size_t n = (size_t)NB * NC * (NL / 4);
    const size_t stride = (size_t)gridDim.x * blockDim.x;
    for (size_t i = (size_t)blockIdx.x * blockDim.x + threadIdx.x; i < n; i += stride) {
        const float s = scale[i >> 10];
        v4f v = xv[i];
        v *= s;
        __builtin_nontemporal_store(v, &ov[i]);
    }
}

extern "C" void kernel_launch(void* const* d_in, const int* in_sizes, int n_in,
                              void* d_out, int out_size, void* d_ws, size_t ws_size,
                              hipStream_t stream) {
    const float* x         = (const float*)d_in[0];
    const float* conv1_w   = (const float*)d_in[1];
    const float* conv2_w   = (const float*)d_in[2];
    const float* combine_w = (const float*)d_in[3];
    const float* combine_b = (const float*)d_in[4];
    const float* ln_g      = (const float*)d_in[5];
    const float* ln_b      = (const float*)d_in[6];
    const float* W1        = (const float*)d_in[7];
    const float* b1        = (const float*)d_in[8];
    const float* W2        = (const float*)d_in[9];
    const float* b2        = (const float*)d_in[10];
    float* out = (float*)d_out;

    float* y        = (float*)d_ws;                    // [0,64KB): pooled means
    float* scale    = y + NB * NC;                     // [64KB,128KB): fallback only
    unsigned* garr  = (unsigned*)(void*)scale;         // coop: overlaps scale region
    unsigned* grel  = garr + GRPS;
    unsigned* root  = grel + GRPS;

    // zero barrier counters each launch (graph-capturable, deterministic)
    hipMemsetAsync((void*)garr, 0, (2 * GRPS + 16) * sizeof(unsigned), stream);

    int nb = 0;
    hipOccupancyMaxActiveBlocksPerMultiprocessor(&nb, fused_kernel, 256, 0);
    if (nb >= NBLK / 256) {
        void* args[] = { (void*)&x, (void*)&y, (void*)&garr, (void*)&grel, (void*)&root,
                         (void*)&conv1_w, (void*)&conv2_w,
                         (void*)&combine_w, (void*)&combine_b,
                         (void*)&ln_g, (void*)&ln_b,
                         (void*)&W1, (void*)&b1, (void*)&W2, (void*)&b2,
                         (void*)&out };
        hipLaunchCooperativeKernel((const void*)fused_kernel, dim3(NBLK), dim3(256),
                                   args, 0, stream);
    } else {
        pool_kernel<<<NB * NC / 4, 256, 0, stream>>>(x, y);
        attn_kernel<<<NB, 1024, 0, stream>>>(y, conv1_w, conv2_w, combine_w, combine_b,
                                             ln_g, ln_b, W1, b1, W2, b2, scale);
        scale_kernel<<<2048, 256, 0, stream>>>(x, scale, out);
    }
}